// Round 2
// baseline (6452.731 us; speedup 1.0000x reference)
//
#include <hip/hip_runtime.h>
#include <hip/hip_bf16.h>

// LSTM decoder, B=1024, H=300, 256 steps. Output dtype: FP32 (reference is fp32).
// Folded recurrence: W_big rows 0..1199 = W_ih@W_out + W_hh (gates from h_{t-1}),
//                    rows 1200..1499 = W_out (y_{t-1} = out from h_{t-1}).
// bias_big[0..1199] = b_ih + b_hh + W_ih@b_out ; [1200..1499] = b_out.
// Step 0 uses W0cat = [W_ih | W_hh] (K=600) on inputs [start | h0], bias0 = b_ih+b_hh.
// All math fp32.

__device__ __forceinline__ float sigf(float x) { return 1.0f / (1.0f + expf(-x)); }

// ---------- precompute: copies ----------
__global__ void build_kernel(const float* __restrict__ W_ih, const float* __restrict__ W_hh,
                             const float* __restrict__ b_ih, const float* __restrict__ b_hh,
                             const float* __restrict__ W_out, const float* __restrict__ b_out,
                             float* __restrict__ W0cat, float* __restrict__ bias0,
                             float* __restrict__ W_big, float* __restrict__ bias_big) {
    int stride = gridDim.x * blockDim.x;
    int idx = blockIdx.x * blockDim.x + threadIdx.x;
    for (int i = idx; i < 1200 * 600; i += stride) {
        int j = i / 600, col = i - j * 600;
        W0cat[i] = (col < 300) ? W_ih[j * 300 + col] : W_hh[j * 300 + col - 300];
    }
    for (int i = idx; i < 300 * 300; i += stride) W_big[1200 * 300 + i] = W_out[i];
    for (int i = idx; i < 1200; i += stride) bias0[i] = b_ih[i] + b_hh[i];
    for (int i = idx; i < 300; i += stride) bias_big[1200 + i] = b_out[i];
}

// ---------- precompute: W_big rows 0..1199 = W_hh + W_ih @ W_out ----------
__global__ __launch_bounds__(128) void fold_kernel(const float* __restrict__ W_ih,
                                                   const float* __restrict__ W_hh,
                                                   const float* __restrict__ W_out,
                                                   float* __restrict__ W_big) {
    int j = blockIdx.x;  // 0..1199
    __shared__ float row[300];
    for (int m = threadIdx.x; m < 300; m += 128) row[m] = W_ih[j * 300 + m];
    __syncthreads();
    int k0 = threadIdx.x, k1 = threadIdx.x + 128, k2 = threadIdx.x + 256;
    float a0 = 0.f, a1 = 0.f, a2 = 0.f;
    for (int m = 0; m < 300; ++m) {
        float w = row[m];
        a0 += w * W_out[m * 300 + k0];
        a1 += w * W_out[m * 300 + k1];
        if (k2 < 300) a2 += w * W_out[m * 300 + k2];
    }
    W_big[j * 300 + k0] = W_hh[j * 300 + k0] + a0;
    W_big[j * 300 + k1] = W_hh[j * 300 + k1] + a1;
    if (k2 < 300) W_big[j * 300 + k2] = W_hh[j * 300 + k2] + a2;
}

// ---------- precompute: bias_big[0..1199] ----------
__global__ __launch_bounds__(64) void bias_fold_kernel(const float* __restrict__ W_ih,
                                                       const float* __restrict__ b_ih,
                                                       const float* __restrict__ b_hh,
                                                       const float* __restrict__ b_out,
                                                       float* __restrict__ bias_big) {
    int j = blockIdx.x;  // 0..1199
    int lane = threadIdx.x;
    float s = 0.f;
    for (int m = lane; m < 300; m += 64) s += W_ih[j * 300 + m] * b_out[m];
    for (int off = 32; off > 0; off >>= 1) s += __shfl_down(s, off);
    if (lane == 0) bias_big[j] = b_ih[j] + b_hh[j] + s;
}

// ---------- fused step ----------
// grid = (16, gate_blocks + y_blocks), block = 128.
// blockIdx.y <  gate_blocks : compute 8 gate-j columns (4 gates each) -> update c, write h_out
// blockIdx.y >= gate_blocks : compute 32 y columns -> write fp32 y_out (out_{t-1})
// GEMM: [64 x K] h tile (LDS, transposed, stride 68) x W rows (LDS [16][32]).
__global__ __launch_bounds__(128) void step_kernel(
    const float* __restrict__ h_in,    // [1024][300]
    const float* __restrict__ x2,      // second half for t=0 (K=600), else null
    const float* __restrict__ W,       // row-major [1500][K] (or [1200][600] at t=0)
    const float* __restrict__ bias,    // [1500] (or [1200])
    int K,
    const float* __restrict__ c_in, float* __restrict__ c_out,
    float* __restrict__ h_out,               // may be null (final y-only launch)
    float* __restrict__ y_out,               // d_out + (t-1)*1024*300, or null
    int gate_blocks) {
    __shared__ float hs[16][68];   // [k][b], pad 68: staging writes 2-way max (free)
    __shared__ float wsm[16][32];  // [k][col]  gate: col=j_local*4+g ; y: col=yj_local

    const int t = threadIdx.x;
    const int bm0 = blockIdx.x * 64;
    const int by = (int)blockIdx.y;
    const bool is_gate = by < gate_blocks;
    const int jg0 = is_gate ? by * 8 : 0;
    const int yj0 = is_gate ? 0 : (by - gate_blocks) * 32;

    // W staging assignment for this thread: one float4 of one row per iter
    const int row_idx = t & 31;
    const int wkq = (t >> 5) << 2;  // 0,4,8,12
    int grow;
    bool wvalid;
    if (is_gate) {
        int jl = row_idx >> 2, g = row_idx & 3;
        grow = jg0 + jl + 300 * g;
        wvalid = (jg0 + jl) < 300;
    } else {
        grow = 1200 + yj0 + row_idx;
        wvalid = (yj0 + row_idx) < 300;
    }

    float acc[4][4];
#pragma unroll
    for (int i = 0; i < 4; ++i)
#pragma unroll
        for (int g = 0; g < 4; ++g) acc[i][g] = 0.f;

    const int niter = (K + 15) >> 4;
    for (int it = 0; it < niter; ++it) {
        const int k0 = it << 4;
        // stage h tile: 64 b x 16 k = 256 float4s, 2 per thread
#pragma unroll
        for (int q = 0; q < 2; ++q) {
            int qi = t + q * 128;
            int bl = qi >> 2;            // 0..63
            int kq = (qi & 3) << 2;      // 0,4,8,12
            int kg = k0 + kq;
            float4 hv = make_float4(0.f, 0.f, 0.f, 0.f);
            if (kg < K) {
                const float* src = (kg < 300) ? (h_in + (size_t)(bm0 + bl) * 300 + kg)
                                              : (x2 + (size_t)(bm0 + bl) * 300 + (kg - 300));
                hv = *(const float4*)src;
            }
            hs[kq + 0][bl] = hv.x;
            hs[kq + 1][bl] = hv.y;
            hs[kq + 2][bl] = hv.z;
            hs[kq + 3][bl] = hv.w;
        }
        // stage W tile: 32 rows x 16 k = 128 float4s, 1 per thread
        {
            int kg = k0 + wkq;
            float4 wv = make_float4(0.f, 0.f, 0.f, 0.f);
            if (wvalid && kg < K) wv = *(const float4*)(W + (size_t)grow * K + kg);
            wsm[wkq + 0][row_idx] = wv.x;
            wsm[wkq + 1][row_idx] = wv.y;
            wsm[wkq + 2][row_idx] = wv.z;
            wsm[wkq + 3][row_idx] = wv.w;
        }
        __syncthreads();
        const int bs4 = (t & 15) << 2;  // 4 consecutive b
        const int c4 = (t >> 4) << 2;   // 4 consecutive cols
#pragma unroll
        for (int k = 0; k < 16; ++k) {
            float4 hv = *(const float4*)&hs[k][bs4];
            float4 wv = *(const float4*)&wsm[k][c4];
            float hvv[4] = {hv.x, hv.y, hv.z, hv.w};
            float wvv[4] = {wv.x, wv.y, wv.z, wv.w};
#pragma unroll
            for (int bi = 0; bi < 4; ++bi)
#pragma unroll
                for (int g = 0; g < 4; ++g) acc[bi][g] += hvv[bi] * wvv[g];
        }
        __syncthreads();
    }

    const int b0 = bm0 + ((t & 15) << 2);
    if (is_gate) {
        const int j = jg0 + (t >> 4);
        if (j < 300) {
            const float bi_ = bias[j];
            const float bf_ = bias[j + 300];
            const float bg_ = bias[j + 600];
            const float bo_ = bias[j + 900];
#pragma unroll
            for (int bi = 0; bi < 4; ++bi) {
                const int b = b0 + bi;
                float ig = sigf(acc[bi][0] + bi_);
                float fg = sigf(acc[bi][1] + bf_);
                float gg = tanhf(acc[bi][2] + bg_);
                float og = sigf(acc[bi][3] + bo_);
                float cn = fg * c_in[(size_t)b * 300 + j] + ig * gg;
                c_out[(size_t)b * 300 + j] = cn;
                if (h_out) h_out[(size_t)b * 300 + j] = og * tanhf(cn);
            }
        }
    } else {
        const int yjb = yj0 + ((t >> 4) << 2);
#pragma unroll
        for (int bi = 0; bi < 4; ++bi) {
            const int b = b0 + bi;
            if (yjb + 3 < 300) {
                float4 tmp;
                tmp.x = acc[bi][0] + bias[1200 + yjb + 0];
                tmp.y = acc[bi][1] + bias[1200 + yjb + 1];
                tmp.z = acc[bi][2] + bias[1200 + yjb + 2];
                tmp.w = acc[bi][3] + bias[1200 + yjb + 3];
                *(float4*)&y_out[(size_t)b * 300 + yjb] = tmp;
            } else {
#pragma unroll
                for (int yi = 0; yi < 4; ++yi) {
                    int yj = yjb + yi;
                    if (yj < 300)
                        y_out[(size_t)b * 300 + yj] = acc[bi][yi] + bias[1200 + yj];
                }
            }
        }
    }
}

extern "C" void kernel_launch(void* const* d_in, const int* in_sizes, int n_in,
                              void* d_out, int out_size, void* d_ws, size_t ws_size,
                              hipStream_t stream) {
    const float* h0 = (const float*)d_in[0];
    const float* c0 = (const float*)d_in[1];
    const float* start = (const float*)d_in[2];
    const float* W_ih = (const float*)d_in[3];
    const float* W_hh = (const float*)d_in[4];
    const float* b_ih = (const float*)d_in[5];
    const float* b_hh = (const float*)d_in[6];
    const float* W_out = (const float*)d_in[7];
    const float* b_out = (const float*)d_in[8];
    float* out = (float*)d_out;

    float* ws = (float*)d_ws;
    float* W0cat = ws;                 // 1200*600 = 720000
    float* W_big = ws + 720000;        // 1500*300 = 450000
    float* bias0 = ws + 1170000;       // 1200
    float* bias_big = ws + 1171200;    // 1500
    float* h_a = ws + 1172700;         // 307200
    float* h_b = ws + 1479900;         // 307200
    float* c_ws = ws + 1787100;        // 307200
    // total 2094300 floats = 8.38 MB

    build_kernel<<<2816, 256, 0, stream>>>(W_ih, W_hh, b_ih, b_hh, W_out, b_out,
                                           W0cat, bias0, W_big, bias_big);
    fold_kernel<<<1200, 128, 0, stream>>>(W_ih, W_hh, W_out, W_big);
    bias_fold_kernel<<<1200, 64, 0, stream>>>(W_ih, b_ih, b_hh, b_out, bias_big);

    // t = 0: gates from [start | h0] (K=600), no y output yet
    step_kernel<<<dim3(16, 38), 128, 0, stream>>>(start, h0, W0cat, bias0, 600,
                                                  c0, c_ws, h_a, nullptr, 38);
    // t = 1..255: gates_t from h_{t-1} via W_big, plus y_{t-1} -> d_out[t-1]
    for (int t = 1; t < 256; ++t) {
        const float* hin = (t & 1) ? h_a : h_b;
        float* hout = (t & 1) ? h_b : h_a;
        step_kernel<<<dim3(16, 48), 128, 0, stream>>>(hin, nullptr, W_big, bias_big, 300,
                                                      c_ws, c_ws, hout,
                                                      out + (size_t)(t - 1) * 307200, 38);
    }
    // t = 256: y_255 only (h_255 is in h_b since t=255 is odd)
    step_kernel<<<dim3(16, 10), 128, 0, stream>>>(h_b, nullptr, W_big, bias_big, 300,
                                                  c_ws, c_ws, nullptr,
                                                  out + (size_t)255 * 307200, 0);
}

// Round 3
// 4842.999 us; speedup vs baseline: 1.3324x; 1.3324x over previous
//
#include <hip/hip_runtime.h>
#include <hip/hip_bf16.h>

// LSTM decoder, B=1024, H=300, 256 steps. Output fp32.
// Folded recurrence (gates_t from h_t only): W_fold = W_hh + W_ih@W_out, 5 channels
// (i,f,g,o,y) packed in MFMA B-fragment layout, split bf16 hi/lo for fp32-grade
// precision via 3 MFMAs per product. h carried in MFMA A-fragment layout hi/lo.
// Step 0 (K=600, [start|h0]) runs an exact fp32 VALU kernel, then converts h.

typedef __attribute__((ext_vector_type(8))) short bf16x8;
typedef __attribute__((ext_vector_type(4))) float f32x4;

__device__ __forceinline__ float sigf(float x) { return 1.0f / (1.0f + __expf(-x)); }
__device__ __forceinline__ float tanh_fast(float x) { return 2.0f / (1.0f + __expf(-2.0f * x)) - 1.0f; }
__device__ __forceinline__ short f2bf(float x) { __hip_bfloat16 h = __float2bfloat16(x); return *(short*)&h; }
__device__ __forceinline__ float bf2f(short s) { __hip_bfloat16 h; *(short*)&h = s; return __bfloat162float(h); }

// ---------- precompute: zero h-frag buffers, copy W_out rows + b_out ----------
__global__ void build_kernel(const float* __restrict__ W_out, const float* __restrict__ b_out,
                             float* __restrict__ W_big, float* __restrict__ bias_big,
                             unsigned int* __restrict__ hfrag_zero) {
    int stride = gridDim.x * blockDim.x;
    int idx = blockIdx.x * blockDim.x + threadIdx.x;
    for (int i = idx; i < 655360; i += stride) hfrag_zero[i] = 0u;  // 4 x 327680 shorts
    for (int i = idx; i < 300 * 300; i += stride) W_big[1200 * 300 + i] = W_out[i];
    for (int i = idx; i < 300; i += stride) bias_big[1200 + i] = b_out[i];
}

// ---------- precompute: W_big rows 0..1199 = W_hh + W_ih @ W_out ----------
__global__ __launch_bounds__(128) void fold_kernel(const float* __restrict__ W_ih,
                                                   const float* __restrict__ W_hh,
                                                   const float* __restrict__ W_out,
                                                   float* __restrict__ W_big) {
    int j = blockIdx.x;  // 0..1199
    __shared__ float row[300];
    for (int m = threadIdx.x; m < 300; m += 128) row[m] = W_ih[j * 300 + m];
    __syncthreads();
    int k0 = threadIdx.x, k1 = threadIdx.x + 128, k2 = threadIdx.x + 256;
    float a0 = 0.f, a1 = 0.f, a2 = 0.f;
    for (int m = 0; m < 300; ++m) {
        float w = row[m];
        a0 += w * W_out[m * 300 + k0];
        a1 += w * W_out[m * 300 + k1];
        if (k2 < 300) a2 += w * W_out[m * 300 + k2];
    }
    W_big[j * 300 + k0] = W_hh[j * 300 + k0] + a0;
    W_big[j * 300 + k1] = W_hh[j * 300 + k1] + a1;
    if (k2 < 300) W_big[j * 300 + k2] = W_hh[j * 300 + k2] + a2;
}

// ---------- precompute: bias_big[0..1199] = b_ih + b_hh + W_ih @ b_out ----------
__global__ __launch_bounds__(64) void bias_fold_kernel(const float* __restrict__ W_ih,
                                                       const float* __restrict__ b_ih,
                                                       const float* __restrict__ b_hh,
                                                       const float* __restrict__ b_out,
                                                       float* __restrict__ bias_big) {
    int j = blockIdx.x;  // 0..1199
    int lane = threadIdx.x;
    float s = 0.f;
    for (int m = lane; m < 300; m += 64) s += W_ih[j * 300 + m] * b_out[m];
    for (int off = 32; off > 0; off >>= 1) s += __shfl_down(s, off);
    if (lane == 0) bias_big[j] = b_ih[j] + b_hh[j] + s;
}

// ---------- precompute: pack W_big into MFMA B-fragment layout, bf16 hi/lo ----------
// tile index = (jt*5 + ch)*10 + kc ; per tile 64 lanes x 8 bf16 (n = jt*16+(lane&15),
// k = kc*32 + (lane>>4)*8 + jj). Channels: 0..3 = gates i,f,g,o (row ch*300+j), 4 = y (row 1200+j).
__global__ __launch_bounds__(64) void pack_w_kernel(const float* __restrict__ W_big,
                                                    short* __restrict__ Wh, short* __restrict__ Wl) {
    int tile = blockIdx.x;  // 0..949
    int jt = tile / 50;
    int rem = tile - jt * 50;
    int ch = rem / 10;
    int kc = rem - ch * 10;
    int lane = threadIdx.x;
    int j = jt * 16 + (lane & 15);
    int kbase = kc * 32 + (lane >> 4) * 8;
    int r = (ch < 4) ? (ch * 300 + j) : (1200 + j);
    size_t base = (size_t)tile * 512 + (size_t)lane * 8;
#pragma unroll
    for (int jj = 0; jj < 8; ++jj) {
        int k = kbase + jj;
        float v = (j < 300 && k < 300) ? W_big[(size_t)r * 300 + k] : 0.f;
        short hi = f2bf(v);
        short lo = f2bf(v - bf2f(hi));
        Wh[base + jj] = hi;
        Wl[base + jj] = lo;
    }
}

// ---------- step 0: exact fp32 VALU LSTM cell on [start | h0], K=600 ----------
__global__ __launch_bounds__(128) void step0_kernel(
    const float* __restrict__ x_in, const float* __restrict__ h_in,
    const float* __restrict__ W_ih, const float* __restrict__ W_hh,
    const float* __restrict__ b_ih, const float* __restrict__ b_hh,
    const float* __restrict__ c_in, float* __restrict__ c_out,
    float* __restrict__ h_out) {
    __shared__ float hs[16][68];
    __shared__ float wsm[16][32];
    const int t = threadIdx.x;
    const int bm0 = blockIdx.x * 64;
    const int jg0 = blockIdx.y * 8;

    const int row_idx = t & 31;
    const int wkq = (t >> 5) << 2;
    const int jl = row_idx >> 2, g = row_idx & 3;
    const int grow = jg0 + jl + 300 * g;
    const bool wvalid = (jg0 + jl) < 300;

    float acc[4][4];
#pragma unroll
    for (int i = 0; i < 4; ++i)
#pragma unroll
        for (int q = 0; q < 4; ++q) acc[i][q] = 0.f;

    for (int it = 0; it < 38; ++it) {  // K=600 -> 38 chunks of 16 (pad)
        const int k0 = it << 4;
#pragma unroll
        for (int q = 0; q < 2; ++q) {
            int qi = t + q * 128;
            int bl = qi >> 2;
            int kq = (qi & 3) << 2;
            int kg = k0 + kq;
            float4 hv = make_float4(0.f, 0.f, 0.f, 0.f);
            if (kg < 600) {
                const float* src = (kg < 300) ? (x_in + (size_t)(bm0 + bl) * 300 + kg)
                                              : (h_in + (size_t)(bm0 + bl) * 300 + (kg - 300));
                hv = *(const float4*)src;
            }
            hs[kq + 0][bl] = hv.x;
            hs[kq + 1][bl] = hv.y;
            hs[kq + 2][bl] = hv.z;
            hs[kq + 3][bl] = hv.w;
        }
        {
            int kg = k0 + wkq;
            float4 wv = make_float4(0.f, 0.f, 0.f, 0.f);
            if (wvalid && kg < 600) {
                const float* src = (kg < 300) ? (W_ih + (size_t)grow * 300 + kg)
                                              : (W_hh + (size_t)grow * 300 + (kg - 300));
                wv = *(const float4*)src;
            }
            wsm[wkq + 0][row_idx] = wv.x;
            wsm[wkq + 1][row_idx] = wv.y;
            wsm[wkq + 2][row_idx] = wv.z;
            wsm[wkq + 3][row_idx] = wv.w;
        }
        __syncthreads();
        const int bs4 = (t & 15) << 2;
        const int c4 = (t >> 4) << 2;
#pragma unroll
        for (int k = 0; k < 16; ++k) {
            float4 hv = *(const float4*)&hs[k][bs4];
            float4 wv = *(const float4*)&wsm[k][c4];
            float hvv[4] = {hv.x, hv.y, hv.z, hv.w};
            float wvv[4] = {wv.x, wv.y, wv.z, wv.w};
#pragma unroll
            for (int bi = 0; bi < 4; ++bi)
#pragma unroll
                for (int q = 0; q < 4; ++q) acc[bi][q] += hvv[bi] * wvv[q];
        }
        __syncthreads();
    }

    const int b0 = bm0 + ((t & 15) << 2);
    const int j = jg0 + (t >> 4);
    if (j < 300) {
        const float bi_ = b_ih[j] + b_hh[j];
        const float bf_ = b_ih[j + 300] + b_hh[j + 300];
        const float bg_ = b_ih[j + 600] + b_hh[j + 600];
        const float bo_ = b_ih[j + 900] + b_hh[j + 900];
#pragma unroll
        for (int bi = 0; bi < 4; ++bi) {
            const int b = b0 + bi;
            float ig = sigf(acc[bi][0] + bi_);
            float fg = sigf(acc[bi][1] + bf_);
            float gg = tanh_fast(acc[bi][2] + bg_);
            float og = sigf(acc[bi][3] + bo_);
            float cn = fg * c_in[(size_t)b * 300 + j] + ig * gg;
            c_out[(size_t)b * 300 + j] = cn;
            h_out[(size_t)b * 300 + j] = og * tanh_fast(cn);
        }
    }
}

// ---------- convert h_row fp32 -> A-fragment layout bf16 hi/lo (zero-pads k 300..319) ----------
__global__ __launch_bounds__(256) void convert_h_kernel(const float* __restrict__ h_row,
                                                        short* __restrict__ Hh, short* __restrict__ Hl) {
    int idx = blockIdx.x * 256 + threadIdx.x;  // 1024*320
    int m = idx >> 5 >> 3;                     // idx / 320... careful: 320 not pow2
    m = idx / 320;
    int k = idx - m * 320;
    float v = (k < 300) ? h_row[(size_t)m * 300 + k] : 0.f;
    short hi = f2bf(v);
    short lo = f2bf(v - bf2f(hi));
    int chunk = k >> 5;
    int lane = (m & 15) + 16 * ((k & 31) >> 3);
    int slot = k & 7;
    size_t fi = (((size_t)(m >> 4) * 10 + chunk) * 64 + lane) * 8 + slot;
    Hh[fi] = hi;
    Hl[fi] = lo;
}

// ---------- MFMA step: gates (i,f,g,o) + y, split-bf16, frag-layout operands ----------
// grid (16, 19), block 128 (2 waves). Wave handles 2 m-subtiles (32 rows) x 1 j-tile x 5 ch.
__global__ __launch_bounds__(128) void mfma_step_kernel(
    const short* __restrict__ Ah, const short* __restrict__ Al,
    const short* __restrict__ Wh, const short* __restrict__ Wl,
    const float* __restrict__ bias,
    float* __restrict__ c_st,
    short* __restrict__ Hh, short* __restrict__ Hl,
    float* __restrict__ y_out,
    const int do_gates) {
    const int lane = threadIdx.x & 63;
    const int wave = threadIdx.x >> 6;
    const int jt = blockIdx.y;
    const int mt0 = blockIdx.x * 4 + wave * 2;

    f32x4 acc[2][5];
#pragma unroll
    for (int a = 0; a < 2; ++a)
#pragma unroll
        for (int c = 0; c < 5; ++c) acc[a][c] = (f32x4){0.f, 0.f, 0.f, 0.f};

    const short* A0h = Ah + (size_t)mt0 * 10 * 512 + (size_t)lane * 8;
    const short* A0l = Al + (size_t)mt0 * 10 * 512 + (size_t)lane * 8;
    const short* Wbh = Wh + (size_t)jt * 50 * 512 + (size_t)lane * 8;
    const short* Wbl = Wl + (size_t)jt * 50 * 512 + (size_t)lane * 8;

#pragma unroll
    for (int kc = 0; kc < 10; ++kc) {
        bf16x8 a0h = *(const bf16x8*)(A0h + kc * 512);
        bf16x8 a0l = *(const bf16x8*)(A0l + kc * 512);
        bf16x8 a1h = *(const bf16x8*)(A0h + (10 + kc) * 512);
        bf16x8 a1l = *(const bf16x8*)(A0l + (10 + kc) * 512);
#pragma unroll
        for (int ch = 0; ch < 5; ++ch) {
            if (!do_gates && ch < 4) continue;
            bf16x8 bh = *(const bf16x8*)(Wbh + (ch * 10 + kc) * 512);
            bf16x8 bl = *(const bf16x8*)(Wbl + (ch * 10 + kc) * 512);
            acc[0][ch] = __builtin_amdgcn_mfma_f32_16x16x32_bf16(a0h, bh, acc[0][ch], 0, 0, 0);
            acc[0][ch] = __builtin_amdgcn_mfma_f32_16x16x32_bf16(a0l, bh, acc[0][ch], 0, 0, 0);
            acc[0][ch] = __builtin_amdgcn_mfma_f32_16x16x32_bf16(a0h, bl, acc[0][ch], 0, 0, 0);
            acc[1][ch] = __builtin_amdgcn_mfma_f32_16x16x32_bf16(a1h, bh, acc[1][ch], 0, 0, 0);
            acc[1][ch] = __builtin_amdgcn_mfma_f32_16x16x32_bf16(a1l, bh, acc[1][ch], 0, 0, 0);
            acc[1][ch] = __builtin_amdgcn_mfma_f32_16x16x32_bf16(a1h, bl, acc[1][ch], 0, 0, 0);
        }
    }

    // epilogue: C/D layout col=lane&15 (=j local), row=(lane>>4)*4+reg (=m local)
    const int j = jt * 16 + (lane & 15);
    if (j >= 300) return;
    const int quad = lane >> 4;
    const float bi_ = bias[j], bf_ = bias[300 + j], bg_ = bias[600 + j],
                bo_ = bias[900 + j], by_ = bias[1200 + j];
    const int chunk = j >> 5;
    const int lb = 16 * ((j & 31) >> 3);
    const int slot = j & 7;
#pragma unroll
    for (int ms = 0; ms < 2; ++ms) {
        const int mt = mt0 + ms;
#pragma unroll
        for (int r = 0; r < 4; ++r) {
            const int m = mt * 16 + quad * 4 + r;
            const size_t cj = (size_t)m * 300 + j;
            if (do_gates) {
                float ig = sigf(acc[ms][0][r] + bi_);
                float fg = sigf(acc[ms][1][r] + bf_);
                float gg = tanh_fast(acc[ms][2][r] + bg_);
                float og = sigf(acc[ms][3][r] + bo_);
                float cn = fg * c_st[cj] + ig * gg;
                c_st[cj] = cn;
                float hv = og * tanh_fast(cn);
                short hb = f2bf(hv);
                short lbits = f2bf(hv - bf2f(hb));
                size_t fi = (((size_t)mt * 10 + chunk) * 64 + (quad * 4 + r + lb)) * 8 + slot;
                Hh[fi] = hb;
                Hl[fi] = lbits;
            }
            y_out[cj] = acc[ms][4][r] + by_;
        }
    }
}

extern "C" void kernel_launch(void* const* d_in, const int* in_sizes, int n_in,
                              void* d_out, int out_size, void* d_ws, size_t ws_size,
                              hipStream_t stream) {
    const float* h0 = (const float*)d_in[0];
    const float* c0 = (const float*)d_in[1];
    const float* start = (const float*)d_in[2];
    const float* W_ih = (const float*)d_in[3];
    const float* W_hh = (const float*)d_in[4];
    const float* b_ih = (const float*)d_in[5];
    const float* b_hh = (const float*)d_in[6];
    const float* W_out = (const float*)d_in[7];
    const float* b_out = (const float*)d_in[8];
    float* out = (float*)d_out;

    float* wsf = (float*)d_ws;
    float* W_big = wsf;               // 450000
    float* bias_big = wsf + 450000;   // 1504
    float* c_ws = wsf + 451504;       // 307200
    float* h_row = wsf + 758704;      // 307200
    short* wss = (short*)(wsf + 1065904);
    short* Wh = wss;                  // 486400
    short* Wl = wss + 486400;         // 486400
    short* H0h = wss + 972800;        // 327680
    short* H0l = wss + 1300480;       // 327680
    short* H1h = wss + 1628160;       // 327680
    short* H1l = wss + 1955840;       // 327680
    // total bytes = 1065904*4 + 2283520*2 = 8,830,656

    build_kernel<<<2816, 256, 0, stream>>>(W_out, b_out, W_big, bias_big, (unsigned int*)H0h);
    fold_kernel<<<1200, 128, 0, stream>>>(W_ih, W_hh, W_out, W_big);
    bias_fold_kernel<<<1200, 64, 0, stream>>>(W_ih, b_ih, b_hh, b_out, bias_big);
    pack_w_kernel<<<950, 64, 0, stream>>>(W_big, Wh, Wl);

    // step 0 (ref iteration 0): exact fp32; h_1 -> h_row, c_1 -> c_ws
    step0_kernel<<<dim3(16, 38), 128, 0, stream>>>(start, h0, W_ih, W_hh, b_ih, b_hh,
                                                   c0, c_ws, h_row);
    convert_h_kernel<<<1280, 256, 0, stream>>>(h_row, H0h, H0l);

    short* Hb[2][2] = {{H0h, H0l}, {H1h, H1l}};
    // tt = 1..255: ref iteration tt (gates from h_tt) + y = out[tt-1] (from h_tt)
    for (int tt = 1; tt < 256; ++tt) {
        short** A = Hb[(tt - 1) & 1];
        short** Hn = Hb[tt & 1];
        mfma_step_kernel<<<dim3(16, 19), 128, 0, stream>>>(
            A[0], A[1], Wh, Wl, bias_big, c_ws, Hn[0], Hn[1],
            out + (size_t)(tt - 1) * 307200, 1);
    }
    // final: out[255] from h_256 (in buf (256-1)&1 = 1)
    mfma_step_kernel<<<dim3(16, 19), 128, 0, stream>>>(
        Hb[1][0], Hb[1][1], Wh, Wl, bias_big, c_ws, Hb[0][0], Hb[0][1],
        out + (size_t)255 * 307200, 0);
}

// Round 4
// 2429.788 us; speedup vs baseline: 2.6557x; 1.9932x over previous
//
#include <hip/hip_runtime.h>
#include <hip/hip_bf16.h>

// LSTM decoder, B=1024, H=300, 256 steps. Output fp32.
// Folded recurrence: W_fold = W_hh + W_ih@W_out (gates from h_t), y = h_t@W_out^T.
// Split-bf16 (hi+lo) MFMA, fp32 accumulate: gates 3 MFMAs/product, y 2 (w_hi only).
// R4: step kernel regrided for occupancy: 608 blocks (32 row-groups x 19 j-tiles),
// 3 waves/block (w0: gates i,f; w1: g,o; w2: y). A staged in LDS per block; gates
// exchanged via LDS for the fused pointwise epilogue (c update, h hi/lo frag write).

typedef __attribute__((ext_vector_type(8))) short bf16x8;
typedef __attribute__((ext_vector_type(4))) float f32x4;

__device__ __forceinline__ float sigf(float x) { return 1.0f / (1.0f + __expf(-x)); }
__device__ __forceinline__ float tanh_fast(float x) { return 2.0f / (1.0f + __expf(-2.0f * x)) - 1.0f; }
__device__ __forceinline__ short f2bf(float x) { __hip_bfloat16 h = __float2bfloat16(x); return *(short*)&h; }
__device__ __forceinline__ float bf2f(short s) { __hip_bfloat16 h; *(short*)&h = s; return __bfloat162float(h); }

// ---------- precompute: zero h-frag buffers, copy W_out rows + b_out ----------
__global__ void build_kernel(const float* __restrict__ W_out, const float* __restrict__ b_out,
                             float* __restrict__ W_big, float* __restrict__ bias_big,
                             unsigned int* __restrict__ hfrag_zero) {
    int stride = gridDim.x * blockDim.x;
    int idx = blockIdx.x * blockDim.x + threadIdx.x;
    for (int i = idx; i < 655360; i += stride) hfrag_zero[i] = 0u;  // 4 x 327680 shorts
    for (int i = idx; i < 300 * 300; i += stride) W_big[1200 * 300 + i] = W_out[i];
    for (int i = idx; i < 300; i += stride) bias_big[1200 + i] = b_out[i];
}

// ---------- precompute: W_big rows 0..1199 = W_hh + W_ih @ W_out ----------
__global__ __launch_bounds__(128) void fold_kernel(const float* __restrict__ W_ih,
                                                   const float* __restrict__ W_hh,
                                                   const float* __restrict__ W_out,
                                                   float* __restrict__ W_big) {
    int j = blockIdx.x;  // 0..1199
    __shared__ float row[300];
    for (int m = threadIdx.x; m < 300; m += 128) row[m] = W_ih[j * 300 + m];
    __syncthreads();
    int k0 = threadIdx.x, k1 = threadIdx.x + 128, k2 = threadIdx.x + 256;
    float a0 = 0.f, a1 = 0.f, a2 = 0.f;
    for (int m = 0; m < 300; ++m) {
        float w = row[m];
        a0 += w * W_out[m * 300 + k0];
        a1 += w * W_out[m * 300 + k1];
        if (k2 < 300) a2 += w * W_out[m * 300 + k2];
    }
    W_big[j * 300 + k0] = W_hh[j * 300 + k0] + a0;
    W_big[j * 300 + k1] = W_hh[j * 300 + k1] + a1;
    if (k2 < 300) W_big[j * 300 + k2] = W_hh[j * 300 + k2] + a2;
}

// ---------- precompute: bias_big[0..1199] = b_ih + b_hh + W_ih @ b_out ----------
__global__ __launch_bounds__(64) void bias_fold_kernel(const float* __restrict__ W_ih,
                                                       const float* __restrict__ b_ih,
                                                       const float* __restrict__ b_hh,
                                                       const float* __restrict__ b_out,
                                                       float* __restrict__ bias_big) {
    int j = blockIdx.x;  // 0..1199
    int lane = threadIdx.x;
    float s = 0.f;
    for (int m = lane; m < 300; m += 64) s += W_ih[j * 300 + m] * b_out[m];
    for (int off = 32; off > 0; off >>= 1) s += __shfl_down(s, off);
    if (lane == 0) bias_big[j] = b_ih[j] + b_hh[j] + s;
}

// ---------- precompute: pack W_big into MFMA B-fragment layout, bf16 hi/lo ----------
// tile index = (jt*5 + ch)*10 + kc ; ch 0..3 = gates (row ch*300+j), 4 = y (row 1200+j).
__global__ __launch_bounds__(64) void pack_w_kernel(const float* __restrict__ W_big,
                                                    short* __restrict__ Wh, short* __restrict__ Wl) {
    int tile = blockIdx.x;  // 0..949
    int jt = tile / 50;
    int rem = tile - jt * 50;
    int ch = rem / 10;
    int kc = rem - ch * 10;
    int lane = threadIdx.x;
    int j = jt * 16 + (lane & 15);
    int kbase = kc * 32 + (lane >> 4) * 8;
    int r = (ch < 4) ? (ch * 300 + j) : (1200 + j);
    size_t base = (size_t)tile * 512 + (size_t)lane * 8;
#pragma unroll
    for (int jj = 0; jj < 8; ++jj) {
        int k = kbase + jj;
        float v = (j < 300 && k < 300) ? W_big[(size_t)r * 300 + k] : 0.f;
        short hi = f2bf(v);
        short lo = f2bf(v - bf2f(hi));
        Wh[base + jj] = hi;
        Wl[base + jj] = lo;
    }
}

// ---------- step 0: exact fp32 VALU LSTM cell on [start | h0], K=600 ----------
__global__ __launch_bounds__(128) void step0_kernel(
    const float* __restrict__ x_in, const float* __restrict__ h_in,
    const float* __restrict__ W_ih, const float* __restrict__ W_hh,
    const float* __restrict__ b_ih, const float* __restrict__ b_hh,
    const float* __restrict__ c_in, float* __restrict__ c_out,
    float* __restrict__ h_out) {
    __shared__ float hs[16][68];
    __shared__ float wsm[16][32];
    const int t = threadIdx.x;
    const int bm0 = blockIdx.x * 64;
    const int jg0 = blockIdx.y * 8;

    const int row_idx = t & 31;
    const int wkq = (t >> 5) << 2;
    const int jl = row_idx >> 2, g = row_idx & 3;
    const int grow = jg0 + jl + 300 * g;
    const bool wvalid = (jg0 + jl) < 300;

    float acc[4][4];
#pragma unroll
    for (int i = 0; i < 4; ++i)
#pragma unroll
        for (int q = 0; q < 4; ++q) acc[i][q] = 0.f;

    for (int it = 0; it < 38; ++it) {
        const int k0 = it << 4;
#pragma unroll
        for (int q = 0; q < 2; ++q) {
            int qi = t + q * 128;
            int bl = qi >> 2;
            int kq = (qi & 3) << 2;
            int kg = k0 + kq;
            float4 hv = make_float4(0.f, 0.f, 0.f, 0.f);
            if (kg < 600) {
                const float* src = (kg < 300) ? (x_in + (size_t)(bm0 + bl) * 300 + kg)
                                              : (h_in + (size_t)(bm0 + bl) * 300 + (kg - 300));
                hv = *(const float4*)src;
            }
            hs[kq + 0][bl] = hv.x;
            hs[kq + 1][bl] = hv.y;
            hs[kq + 2][bl] = hv.z;
            hs[kq + 3][bl] = hv.w;
        }
        {
            int kg = k0 + wkq;
            float4 wv = make_float4(0.f, 0.f, 0.f, 0.f);
            if (wvalid && kg < 600) {
                const float* src = (kg < 300) ? (W_ih + (size_t)grow * 300 + kg)
                                              : (W_hh + (size_t)grow * 300 + (kg - 300));
                wv = *(const float4*)src;
            }
            wsm[wkq + 0][row_idx] = wv.x;
            wsm[wkq + 1][row_idx] = wv.y;
            wsm[wkq + 2][row_idx] = wv.z;
            wsm[wkq + 3][row_idx] = wv.w;
        }
        __syncthreads();
        const int bs4 = (t & 15) << 2;
        const int c4 = (t >> 4) << 2;
#pragma unroll
        for (int k = 0; k < 16; ++k) {
            float4 hv = *(const float4*)&hs[k][bs4];
            float4 wv = *(const float4*)&wsm[k][c4];
            float hvv[4] = {hv.x, hv.y, hv.z, hv.w};
            float wvv[4] = {wv.x, wv.y, wv.z, wv.w};
#pragma unroll
            for (int bi = 0; bi < 4; ++bi)
#pragma unroll
                for (int q = 0; q < 4; ++q) acc[bi][q] += hvv[bi] * wvv[q];
        }
        __syncthreads();
    }

    const int b0 = bm0 + ((t & 15) << 2);
    const int j = jg0 + (t >> 4);
    if (j < 300) {
        const float bi_ = b_ih[j] + b_hh[j];
        const float bf_ = b_ih[j + 300] + b_hh[j + 300];
        const float bg_ = b_ih[j + 600] + b_hh[j + 600];
        const float bo_ = b_ih[j + 900] + b_hh[j + 900];
#pragma unroll
        for (int bi = 0; bi < 4; ++bi) {
            const int b = b0 + bi;
            float ig = sigf(acc[bi][0] + bi_);
            float fg = sigf(acc[bi][1] + bf_);
            float gg = tanh_fast(acc[bi][2] + bg_);
            float og = sigf(acc[bi][3] + bo_);
            float cn = fg * c_in[(size_t)b * 300 + j] + ig * gg;
            c_out[(size_t)b * 300 + j] = cn;
            h_out[(size_t)b * 300 + j] = og * tanh_fast(cn);
        }
    }
}

// ---------- convert h fp32 -> A-fragment layout bf16 hi/lo ----------
__global__ __launch_bounds__(256) void convert_h_kernel(const float* __restrict__ h_row,
                                                        short* __restrict__ Hh, short* __restrict__ Hl) {
    int idx = blockIdx.x * 256 + threadIdx.x;  // 1024*320
    int m = idx / 320;
    int k = idx - m * 320;
    float v = (k < 300) ? h_row[(size_t)m * 300 + k] : 0.f;
    short hi = f2bf(v);
    short lo = f2bf(v - bf2f(hi));
    int chunk = k >> 5;
    int lane = (m & 15) + 16 * ((k & 31) >> 3);
    int slot = k & 7;
    size_t fi = (((size_t)(m >> 4) * 10 + chunk) * 64 + lane) * 8 + slot;
    Hh[fi] = hi;
    Hl[fi] = lo;
}

// ---------- R4 MFMA step: 608 blocks (32 rowgrp x 19 jt), 192 threads (3 waves) ----------
// w0: gates i,f ; w1: gates g,o ; w2: y. A (2 m-tiles) staged in LDS; gates -> LDS;
// pointwise epilogue updates c, writes next-h fragments (hi/lo), y written direct.
__global__ __launch_bounds__(192, 2) void step_kernel(
    const short* __restrict__ Ah, const short* __restrict__ Al,   // cur h frags
    short* __restrict__ Bh, short* __restrict__ Bl,               // next h frags
    const short* __restrict__ Wh, const short* __restrict__ Wl,
    const float* __restrict__ bias,
    float* __restrict__ c_st,
    float* __restrict__ y_out) {
    const int bid = blockIdx.x;
    const int jt = bid >> 5;          // 0..18
    const int mxp = bid & 31;         // 0..31 -> rows mxp*32 .. +32
    const int tid = threadIdx.x;
    const int wave = tid >> 6;
    const int lane = tid & 63;

    __shared__ short As_h[2 * 10 * 512];   // 20 KB
    __shared__ short As_l[2 * 10 * 512];   // 20 KB
    __shared__ float gbuf[4][32][16];      // 8 KB

    // stage A (2 m-tiles worth of fragments) into LDS
    {
        const size_t abase = (size_t)(mxp * 2) * 10 * 512;
        const int4* gAh = (const int4*)(Ah + abase);
        const int4* gAl = (const int4*)(Al + abase);
        int4* sAh = (int4*)As_h;
        int4* sAl = (int4*)As_l;
        for (int i = tid; i < 1280; i += 192) {
            sAh[i] = gAh[i];
            sAl[i] = gAl[i];
        }
    }
    __syncthreads();

    const short* aoff_h = As_h + lane * 8;
    const short* aoff_l = As_l + lane * 8;

    if (wave < 2) {
        const int ch0 = wave * 2;
        f32x4 acc[2][2];  // [chl][mt]
#pragma unroll
        for (int a = 0; a < 2; ++a)
#pragma unroll
            for (int b = 0; b < 2; ++b) acc[a][b] = (f32x4){0.f, 0.f, 0.f, 0.f};

        const short* wb_h[2] = {Wh + ((size_t)(jt * 5 + ch0) * 10) * 512 + lane * 8,
                                Wh + ((size_t)(jt * 5 + ch0 + 1) * 10) * 512 + lane * 8};
        const short* wb_l[2] = {Wl + ((size_t)(jt * 5 + ch0) * 10) * 512 + lane * 8,
                                Wl + ((size_t)(jt * 5 + ch0 + 1) * 10) * 512 + lane * 8};
#pragma unroll 2
        for (int kc = 0; kc < 10; ++kc) {
            bf16x8 a0h = *(const bf16x8*)(aoff_h + kc * 512);
            bf16x8 a0l = *(const bf16x8*)(aoff_l + kc * 512);
            bf16x8 a1h = *(const bf16x8*)(aoff_h + (10 + kc) * 512);
            bf16x8 a1l = *(const bf16x8*)(aoff_l + (10 + kc) * 512);
#pragma unroll
            for (int chl = 0; chl < 2; ++chl) {
                bf16x8 bh = *(const bf16x8*)(wb_h[chl] + kc * 512);
                bf16x8 bl = *(const bf16x8*)(wb_l[chl] + kc * 512);
                acc[chl][0] = __builtin_amdgcn_mfma_f32_16x16x32_bf16(a0h, bh, acc[chl][0], 0, 0, 0);
                acc[chl][0] = __builtin_amdgcn_mfma_f32_16x16x32_bf16(a0l, bh, acc[chl][0], 0, 0, 0);
                acc[chl][0] = __builtin_amdgcn_mfma_f32_16x16x32_bf16(a0h, bl, acc[chl][0], 0, 0, 0);
                acc[chl][1] = __builtin_amdgcn_mfma_f32_16x16x32_bf16(a1h, bh, acc[chl][1], 0, 0, 0);
                acc[chl][1] = __builtin_amdgcn_mfma_f32_16x16x32_bf16(a1l, bh, acc[chl][1], 0, 0, 0);
                acc[chl][1] = __builtin_amdgcn_mfma_f32_16x16x32_bf16(a1h, bl, acc[chl][1], 0, 0, 0);
            }
        }
        // gates -> LDS. C/D: col=lane&15 (j local), row=(lane>>4)*4+r (m within tile)
        const int jl = lane & 15;
        const int mr = (lane >> 4) * 4;
#pragma unroll
        for (int chl = 0; chl < 2; ++chl)
#pragma unroll
            for (int mt = 0; mt < 2; ++mt)
#pragma unroll
                for (int r = 0; r < 4; ++r)
                    gbuf[ch0 + chl][mt * 16 + mr + r][jl] = acc[chl][mt][r];
    } else {
        // y wave: 2 MFMAs per (mt,kc): (a_hi + a_lo) x w_hi
        f32x4 accy[2];
        accy[0] = (f32x4){0.f, 0.f, 0.f, 0.f};
        accy[1] = (f32x4){0.f, 0.f, 0.f, 0.f};
        const short* wy = Wh + ((size_t)(jt * 5 + 4) * 10) * 512 + lane * 8;
#pragma unroll 2
        for (int kc = 0; kc < 10; ++kc) {
            bf16x8 a0h = *(const bf16x8*)(aoff_h + kc * 512);
            bf16x8 a0l = *(const bf16x8*)(aoff_l + kc * 512);
            bf16x8 a1h = *(const bf16x8*)(aoff_h + (10 + kc) * 512);
            bf16x8 a1l = *(const bf16x8*)(aoff_l + (10 + kc) * 512);
            bf16x8 bh = *(const bf16x8*)(wy + kc * 512);
            accy[0] = __builtin_amdgcn_mfma_f32_16x16x32_bf16(a0h, bh, accy[0], 0, 0, 0);
            accy[0] = __builtin_amdgcn_mfma_f32_16x16x32_bf16(a0l, bh, accy[0], 0, 0, 0);
            accy[1] = __builtin_amdgcn_mfma_f32_16x16x32_bf16(a1h, bh, accy[1], 0, 0, 0);
            accy[1] = __builtin_amdgcn_mfma_f32_16x16x32_bf16(a1l, bh, accy[1], 0, 0, 0);
        }
        const int j = jt * 16 + (lane & 15);
        if (j < 300) {
            const float by = bias[1200 + j];
            const int mr = (lane >> 4) * 4;
#pragma unroll
            for (int mt = 0; mt < 2; ++mt)
#pragma unroll
                for (int r = 0; r < 4; ++r) {
                    const int m = mxp * 32 + mt * 16 + mr + r;
                    y_out[(size_t)m * 300 + j] = accy[mt][r] + by;
                }
        }
    }
    __syncthreads();

    // pointwise epilogue: 512 elems (32 m x 16 j)
    for (int e = tid; e < 512; e += 192) {
        const int ml = e >> 4;
        const int jl = e & 15;
        const int j = jt * 16 + jl;
        if (j >= 300) continue;
        const int m = mxp * 32 + ml;
        float gi = gbuf[0][ml][jl] + bias[j];
        float gf = gbuf[1][ml][jl] + bias[300 + j];
        float gg = gbuf[2][ml][jl] + bias[600 + j];
        float go = gbuf[3][ml][jl] + bias[900 + j];
        float iv = sigf(gi), fv = sigf(gf), gv = tanh_fast(gg), ov = sigf(go);
        const size_t cj = (size_t)m * 300 + j;
        float cn = fv * c_st[cj] + iv * gv;
        c_st[cj] = cn;
        float hv = ov * tanh_fast(cn);
        short hb = f2bf(hv);
        short lb = f2bf(hv - bf2f(hb));
        const int chunk = j >> 5;
        const int lane_a = (m & 15) + 16 * ((j & 31) >> 3);
        const int slot = j & 7;
        const size_t fi = (((size_t)(m >> 4) * 10 + chunk) * 64 + lane_a) * 8 + slot;
        Bh[fi] = hb;
        Bl[fi] = lb;
    }
}

extern "C" void kernel_launch(void* const* d_in, const int* in_sizes, int n_in,
                              void* d_out, int out_size, void* d_ws, size_t ws_size,
                              hipStream_t stream) {
    const float* h0 = (const float*)d_in[0];
    const float* c0 = (const float*)d_in[1];
    const float* start = (const float*)d_in[2];
    const float* W_ih = (const float*)d_in[3];
    const float* W_hh = (const float*)d_in[4];
    const float* b_ih = (const float*)d_in[5];
    const float* b_hh = (const float*)d_in[6];
    const float* W_out = (const float*)d_in[7];
    const float* b_out = (const float*)d_in[8];
    float* out = (float*)d_out;

    float* wsf = (float*)d_ws;
    float* W_big = wsf;               // 450000
    float* bias_big = wsf + 450000;   // 1504
    float* c_ws = wsf + 451504;       // 307200
    float* h_row = wsf + 758704;      // 307200
    short* wss = (short*)(wsf + 1065904);
    short* Wh = wss;                  // 486400
    short* Wl = wss + 486400;         // 486400
    short* H0h = wss + 972800;        // 327680
    short* H0l = wss + 1300480;       // 327680
    short* H1h = wss + 1628160;       // 327680
    short* H1l = wss + 1955840;       // 327680

    build_kernel<<<2816, 256, 0, stream>>>(W_out, b_out, W_big, bias_big, (unsigned int*)H0h);
    fold_kernel<<<1200, 128, 0, stream>>>(W_ih, W_hh, W_out, W_big);
    bias_fold_kernel<<<1200, 64, 0, stream>>>(W_ih, b_ih, b_hh, b_out, bias_big);
    pack_w_kernel<<<950, 64, 0, stream>>>(W_big, Wh, Wl);

    // step 0 (ref iteration 0): exact fp32; h_1 -> h_row, c_1 -> c_ws
    step0_kernel<<<dim3(16, 38), 128, 0, stream>>>(start, h0, W_ih, W_hh, b_ih, b_hh,
                                                   c0, c_ws, h_row);
    convert_h_kernel<<<1280, 256, 0, stream>>>(h_row, H0h, H0l);

    short* Hb[2][2] = {{H0h, H0l}, {H1h, H1l}};
    // tt = 1..256: gates from h_tt -> h_{tt+1}; y = h_tt@W_out^T + b = out[tt-1]
    for (int tt = 1; tt <= 256; ++tt) {
        short** A = Hb[(tt - 1) & 1];
        short** Bn = Hb[tt & 1];
        step_kernel<<<608, 192, 0, stream>>>(A[0], A[1], Bn[0], Bn[1], Wh, Wl,
                                             bias_big, c_ws,
                                             out + (size_t)(tt - 1) * 307200);
    }
}